// Round 2
// baseline (1556.922 us; speedup 1.0000x reference)
//
#include <hip/hip_runtime.h>
#include <cstdint>

// Problem constants
#define BB 4
#define LL 1024
#define DM 512
#define DI 1024
#define DS 16
#define DTR 32
#define NX 64          // DTR + 2*DS
#define MROWS 4096     // B*L

// ---------------------------------------------------------------------------
// Generic tiled GEMM: C[M,N] (f32) = A[M,K] (f32, lda) @ Bw[K,N] (f32, ldb=N)
// EP: 0 = plain store, 1 = softplus(acc + bias[col]) store, 2 = atomicAdd (split-K)
// grid: (N/64, M/64, ksplit); kchunk = K / ksplit (multiple of 16)
template <int EP>
__global__ __launch_bounds__(256) void gemm_k(
    const float* __restrict__ A, const float* __restrict__ Bw, float* __restrict__ C,
    int M, int N, int K, int lda, const float* __restrict__ bias, int kchunk)
{
    __shared__ float As[16][68];
    __shared__ float Bs[16][68];
    const int tid = threadIdx.x;
    const int tx = tid & 15, ty = tid >> 4;
    const int col0 = blockIdx.x * 64, row0 = blockIdx.y * 64;
    const int kstart = blockIdx.z * kchunk;
    const int kend = kstart + kchunk;

    float acc[4][4];
#pragma unroll
    for (int i = 0; i < 4; ++i)
#pragma unroll
        for (int j = 0; j < 4; ++j) acc[i][j] = 0.f;

    const int am = tid >> 2;          // 0..63 (row within tile)
    const int ak = (tid & 3) * 4;     // 0,4,8,12 (k within tile)
    const int bk = tid >> 4;          // 0..15
    const int bn = (tid & 15) * 4;    // 0..60

    for (int k0 = kstart; k0 < kend; k0 += 16) {
        float4 av = *(const float4*)(A + (size_t)(row0 + am) * lda + k0 + ak);
        float4 bv = *(const float4*)(Bw + (size_t)(k0 + bk) * N + col0 + bn);
        __syncthreads();
        As[ak + 0][am] = av.x; As[ak + 1][am] = av.y;
        As[ak + 2][am] = av.z; As[ak + 3][am] = av.w;
        Bs[bk][bn + 0] = bv.x; Bs[bk][bn + 1] = bv.y;
        Bs[bk][bn + 2] = bv.z; Bs[bk][bn + 3] = bv.w;
        __syncthreads();
#pragma unroll
        for (int k = 0; k < 16; ++k) {
            const float4 a = *(const float4*)&As[k][ty * 4];
            const float4 b = *(const float4*)&Bs[k][tx * 4];
            acc[0][0] += a.x * b.x; acc[0][1] += a.x * b.y; acc[0][2] += a.x * b.z; acc[0][3] += a.x * b.w;
            acc[1][0] += a.y * b.x; acc[1][1] += a.y * b.y; acc[1][2] += a.y * b.z; acc[1][3] += a.y * b.w;
            acc[2][0] += a.z * b.x; acc[2][1] += a.z * b.y; acc[2][2] += a.z * b.z; acc[2][3] += a.z * b.w;
            acc[3][0] += a.w * b.x; acc[3][1] += a.w * b.y; acc[3][2] += a.w * b.z; acc[3][3] += a.w * b.w;
        }
    }

#pragma unroll
    for (int i = 0; i < 4; ++i) {
        int row = row0 + ty * 4 + i;
#pragma unroll
        for (int j = 0; j < 4; ++j) {
            int col = col0 + tx * 4 + j;
            float v = acc[i][j];
            size_t addr = (size_t)row * N + col;
            if (EP == 1) {
                v += bias[col];
                // numerically-stable softplus: max(v,0) + log1p(exp(-|v|))
                float ax = fabsf(v);
                v = fmaxf(v, 0.f) + log1pf(__expf(-ax));
                C[addr] = v;
            } else if (EP == 2) {
                atomicAdd(&C[addr], v);
            } else {
                C[addr] = v;
            }
        }
    }
}

// ---------------------------------------------------------------------------
// depthwise causal conv (kernel 4) + bias + SiLU
// reads xin = xz[..., 0:DI]; writes xs (f32)
__global__ void conv_silu_kernel(const float* __restrict__ xz,
                                 const float* __restrict__ cw, const float* __restrict__ cb,
                                 float* __restrict__ xs)
{
    int idx = blockIdx.x * blockDim.x + threadIdx.x;   // 0 .. 4M-1
    int d = idx & (DI - 1);
    int bt = idx >> 10;
    int t = bt & (LL - 1);
    float acc = cb[d];
#pragma unroll
    for (int k = 0; k < 4; ++k) {
        int tt = t - 3 + k;
        if (tt >= 0) acc += xz[(size_t)(bt - 3 + k) * 2048 + d] * cw[d * 4 + k];
    }
    xs[idx] = acc / (1.f + __expf(-acc));
}

// ---------------------------------------------------------------------------
// selective scan; thread per (b, d, n). Writes yz = (y + xs*Dsk) * silu(z)
// yz aliases delta (in place): iteration t's read of delta[t+1] is consumed
// (waitcnt) before iteration t+1 overwrites that address; same wave owns both.
// delta/yz deliberately NOT __restrict__.
__global__ __launch_bounds__(1024) void scan_kernel(
    const float* delta, const float* __restrict__ xs,
    const float* __restrict__ dbc, const float* __restrict__ xz,
    const float* __restrict__ A_log, const float* __restrict__ Dsk,
    float* yz)
{
    int tid = blockIdx.x * 1024 + threadIdx.x;
    int n = tid & 15;
    int d = (tid >> 4) & (DI - 1);
    int b = tid >> 14;
    float An = -__expf(A_log[d * 16 + n]);
    float Dd = Dsk[d];
    float h = 0.f;
    int base = b * LL;

    float dlt = delta[(size_t)base * DI + d];
    float xv  = xs[(size_t)base * DI + d];
    float Bn  = dbc[(size_t)base * NX + DTR + n];
    float Cn  = dbc[(size_t)base * NX + DTR + DS + n];
    float zv  = xz[(size_t)base * 2048 + DI + d];

    for (int t = 0; t < LL; ++t) {
        float dlt1 = 0.f, xv1 = 0.f, Bn1 = 0.f, Cn1 = 0.f, zv1 = 0.f;
        if (t + 1 < LL) {
            int bt1 = base + t + 1;
            dlt1 = delta[(size_t)bt1 * DI + d];
            xv1  = xs[(size_t)bt1 * DI + d];
            Bn1  = dbc[(size_t)bt1 * NX + DTR + n];
            Cn1  = dbc[(size_t)bt1 * NX + DTR + DS + n];
            zv1  = xz[(size_t)bt1 * 2048 + DI + d];
        }
        float dA = __expf(dlt * An);
        h = fmaf(dA, h, dlt * xv * Bn);
        float p = h * Cn;
        p += __shfl_xor(p, 1);
        p += __shfl_xor(p, 2);
        p += __shfl_xor(p, 4);
        p += __shfl_xor(p, 8);
        if (n == 0) {
            float y = p + xv * Dd;
            float sz = zv / (1.f + __expf(-zv));
            yz[(size_t)(base + t) * DI + d] = y * sz;
        }
        dlt = dlt1; xv = xv1; Bn = Bn1; Cn = Cn1; zv = zv1;
    }
}

// ---------------------------------------------------------------------------
// residual add + LayerNorm; hprev and hout must not alias
__global__ __launch_bounds__(512) void ln_kernel(
    const float* __restrict__ o, const float* __restrict__ hprev,
    const float* __restrict__ g, const float* __restrict__ bta,
    float* __restrict__ hout)
{
    int row = blockIdx.x, c = threadIdx.x;
    size_t off = (size_t)row * DM + c;
    float v = o[off] + hprev[off];
    float s1 = v, s2 = v * v;
#pragma unroll
    for (int m = 32; m >= 1; m >>= 1) {
        s1 += __shfl_xor(s1, m);
        s2 += __shfl_xor(s2, m);
    }
    __shared__ float r1[8], r2[8];
    __shared__ float stats[2];
    int w = c >> 6;
    if ((c & 63) == 0) { r1[w] = s1; r2[w] = s2; }
    __syncthreads();
    if (c == 0) {
        float a = 0.f, q = 0.f;
        for (int i = 0; i < 8; ++i) { a += r1[i]; q += r2[i]; }
        float mean = a / (float)DM;
        float var = q / (float)DM - mean * mean;
        stats[0] = mean;
        stats[1] = rsqrtf(var + 1e-5f);
    }
    __syncthreads();
    hout[off] = (v - stats[0]) * stats[1] * g[c] + bta[c];
}

// ---------------------------------------------------------------------------
extern "C" void kernel_launch(void* const* d_in, const int* in_sizes, int n_in,
                              void* d_out, int out_size, void* d_ws, size_t ws_size,
                              hipStream_t stream)
{
    const float* x    = (const float*)d_in[0];
    const float* Wi   = (const float*)d_in[1];
    const float* cw   = (const float*)d_in[2];
    const float* cb   = (const float*)d_in[3];
    const float* Wx   = (const float*)d_in[4];
    const float* Wdt  = (const float*)d_in[5];
    const float* bdt  = (const float*)d_in[6];
    const float* Alog = (const float*)d_in[7];
    const float* Dsk  = (const float*)d_in[8];
    const float* Wo   = (const float*)d_in[9];
    const float* lng  = (const float*)d_in[10];
    const float* lnb  = (const float*)d_in[11];

    // workspace layout (floats). total 20.25M floats = 81 MB
    float* ws   = (float*)d_ws;
    float* h    = ws;                        // 2M   (4096 x 512)
    float* xzb  = h + 2 * 1024 * 1024;       // 8M   (4096 x 2048)
    float* xsb  = xzb + 8 * 1024 * 1024;     // 4M   (4096 x 1024)
    float* dbc  = xsb + 4 * 1024 * 1024;     // 256K (4096 x 64)
    float* dlt  = dbc + 262144;              // 4M   (4096 x 1024); scan writes yz here in place
    float* ob   = dlt + 4 * 1024 * 1024;     // 2M   (4096 x 512)

    for (int l = 0; l < 2; ++l) {
        const float* hin = (l == 0) ? x : h;

        // xz = hin @ Wi[l]   (4096 x 2048, K=512)
        gemm_k<0><<<dim3(2048 / 64, MROWS / 64, 1), 256, 0, stream>>>(
            hin, Wi + (size_t)l * DM * 2048, xzb, MROWS, 2048, DM, DM, nullptr, DM);

        // xs = silu(conv(xin) + cb)
        conv_silu_kernel<<<MROWS * DI / 256, 256, 0, stream>>>(
            xzb, cw + (size_t)l * DI * 4, cb + (size_t)l * DI, xsb);

        // dbc = xs @ Wx[l]  (4096 x 64, K=1024, split-K=8 with atomics)
        hipMemsetAsync(dbc, 0, (size_t)MROWS * NX * sizeof(float), stream);
        gemm_k<2><<<dim3(1, MROWS / 64, 8), 256, 0, stream>>>(
            xsb, Wx + (size_t)l * DI * NX, dbc, MROWS, NX, DI, DI, nullptr, DI / 8);

        // delta = softplus(dbc[:, :32] @ Wdt[l] + bdt[l])  (4096 x 1024, K=32)
        gemm_k<1><<<dim3(DI / 64, MROWS / 64, 1), 256, 0, stream>>>(
            dbc, Wdt + (size_t)l * DTR * DI, dlt, MROWS, DI, DTR, NX,
            bdt + (size_t)l * DI, DTR);

        // selective scan -> yz (in place over dlt)
        scan_kernel<<<64, 1024, 0, stream>>>(
            dlt, xsb, dbc, xzb, Alog + (size_t)l * DI * DS, Dsk + (size_t)l * DI, dlt);

        // o = yz @ Wo[l]  (4096 x 512, K=1024)
        gemm_k<0><<<dim3(DM / 64, MROWS / 64, 1), 256, 0, stream>>>(
            dlt, Wo + (size_t)l * DI * DM, ob, MROWS, DM, DI, DI, nullptr, DI);

        // h = LN(o + hin); last layer writes d_out (f32)
        ln_kernel<<<MROWS, 512, 0, stream>>>(
            ob, hin, lng + (size_t)l * DM, lnb + (size_t)l * DM,
            (l == 1) ? (float*)d_out : h);
    }
}

// Round 3
// 894.773 us; speedup vs baseline: 1.7400x; 1.7400x over previous
//
#include <hip/hip_runtime.h>
#include <cstdint>

// Problem constants
#define BB 4
#define LL 1024
#define DM 512
#define DI 1024
#define DS 16
#define DTR 32
#define NX 64          // DTR + 2*DS
#define MROWS 4096     // B*L
#define CH 64          // scan chunk length
#define NCH 16         // LL / CH

// ---------------------------------------------------------------------------
// Generic tiled GEMM: C[M,N] (f32) = A[M,K] (f32, lda) @ Bw[K,N] (f32, ldb=N)
// EP: 0 = plain store, 1 = softplus(acc + bias[col]) store, 2 = atomicAdd (split-K)
// grid: (N/64, M/64, ksplit); kchunk = K / ksplit (multiple of 16)
template <int EP>
__global__ __launch_bounds__(256) void gemm_k(
    const float* __restrict__ A, const float* __restrict__ Bw, float* __restrict__ C,
    int M, int N, int K, int lda, const float* __restrict__ bias, int kchunk)
{
    __shared__ float As[16][68];
    __shared__ float Bs[16][68];
    const int tid = threadIdx.x;
    const int tx = tid & 15, ty = tid >> 4;
    const int col0 = blockIdx.x * 64, row0 = blockIdx.y * 64;
    const int kstart = blockIdx.z * kchunk;
    const int kend = kstart + kchunk;

    float acc[4][4];
#pragma unroll
    for (int i = 0; i < 4; ++i)
#pragma unroll
        for (int j = 0; j < 4; ++j) acc[i][j] = 0.f;

    const int am = tid >> 2;          // 0..63 (row within tile)
    const int ak = (tid & 3) * 4;     // 0,4,8,12 (k within tile)
    const int bk = tid >> 4;          // 0..15
    const int bn = (tid & 15) * 4;    // 0..60

    for (int k0 = kstart; k0 < kend; k0 += 16) {
        float4 av = *(const float4*)(A + (size_t)(row0 + am) * lda + k0 + ak);
        float4 bv = *(const float4*)(Bw + (size_t)(k0 + bk) * N + col0 + bn);
        __syncthreads();
        As[ak + 0][am] = av.x; As[ak + 1][am] = av.y;
        As[ak + 2][am] = av.z; As[ak + 3][am] = av.w;
        Bs[bk][bn + 0] = bv.x; Bs[bk][bn + 1] = bv.y;
        Bs[bk][bn + 2] = bv.z; Bs[bk][bn + 3] = bv.w;
        __syncthreads();
#pragma unroll
        for (int k = 0; k < 16; ++k) {
            const float4 a = *(const float4*)&As[k][ty * 4];
            const float4 b = *(const float4*)&Bs[k][tx * 4];
            acc[0][0] += a.x * b.x; acc[0][1] += a.x * b.y; acc[0][2] += a.x * b.z; acc[0][3] += a.x * b.w;
            acc[1][0] += a.y * b.x; acc[1][1] += a.y * b.y; acc[1][2] += a.y * b.z; acc[1][3] += a.y * b.w;
            acc[2][0] += a.z * b.x; acc[2][1] += a.z * b.y; acc[2][2] += a.z * b.z; acc[2][3] += a.z * b.w;
            acc[3][0] += a.w * b.x; acc[3][1] += a.w * b.y; acc[3][2] += a.w * b.z; acc[3][3] += a.w * b.w;
        }
    }

#pragma unroll
    for (int i = 0; i < 4; ++i) {
        int row = row0 + ty * 4 + i;
#pragma unroll
        for (int j = 0; j < 4; ++j) {
            int col = col0 + tx * 4 + j;
            float v = acc[i][j];
            size_t addr = (size_t)row * N + col;
            if (EP == 1) {
                v += bias[col];
                float ax = fabsf(v);
                v = fmaxf(v, 0.f) + log1pf(__expf(-ax));
                C[addr] = v;
            } else if (EP == 2) {
                atomicAdd(&C[addr], v);
            } else {
                C[addr] = v;
            }
        }
    }
}

// ---------------------------------------------------------------------------
// depthwise causal conv (kernel 4) + bias + SiLU
__global__ void conv_silu_kernel(const float* __restrict__ xz,
                                 const float* __restrict__ cw, const float* __restrict__ cb,
                                 float* __restrict__ xs)
{
    int idx = blockIdx.x * blockDim.x + threadIdx.x;   // 0 .. 4M-1
    int d = idx & (DI - 1);
    int bt = idx >> 10;
    int t = bt & (LL - 1);
    float acc = cb[d];
#pragma unroll
    for (int k = 0; k < 4; ++k) {
        int tt = t - 3 + k;
        if (tt >= 0) acc += xz[(size_t)(bt - 3 + k) * 2048 + d] * cw[d * 4 + k];
    }
    xs[idx] = acc / (1.f + __expf(-acc));
}

// ---------------------------------------------------------------------------
// Chunked parallel scan. Recurrence h_t = dA_t*h_{t-1} + dBu_t is linear and
// diagonal in the state dim, so a chunk composes as H_out = P*H_in + Q with
// P = prod(dA), Q = local scan from 0 -- elementwise per (b,d,n).
//
// pass1: thread per (b,chunk,d,n); local scan over CH steps -> (P,Q)
__global__ __launch_bounds__(1024) void scan_pass1(
    const float* __restrict__ delta, const float* __restrict__ xs,
    const float* __restrict__ dbc, const float* __restrict__ A_log,
    float* __restrict__ P, float* __restrict__ Q)
{
    const int tid = threadIdx.x;
    const int n = tid & 15;
    const int dlo = (tid >> 4) & 63;          // 64 d per block
    const int dgrp = blockIdx.x & 15;
    const int chunk = (blockIdx.x >> 4) & 15;
    const int b = blockIdx.x >> 8;
    const int d = dgrp * 64 + dlo;
    const float An = -__expf(A_log[d * DS + n]);
    const int t0 = b * LL + chunk * CH;
    const float* dp = delta + (size_t)t0 * DI + d;
    const float* xp = xs + (size_t)t0 * DI + d;
    const float* bp = dbc + (size_t)t0 * NX + DTR + n;
    float Pv = 1.f, h = 0.f;
    for (int t = 0; t < CH; ++t) {
        float dlt = dp[t * DI];
        float xv  = xp[t * DI];
        float Bn  = bp[t * NX];
        float dA = __expf(dlt * An);
        Pv *= dA;
        h = fmaf(dA, h, dlt * xv * Bn);
    }
    size_t idx = ((size_t)(b * NCH + chunk) * DI + d) * DS + n;
    P[idx] = Pv;
    Q[idx] = h;
}

// pass2: thread per (b,d,n); serial scan over NCH chunks; P[idx] becomes H_in
__global__ __launch_bounds__(256) void scan_pass2(float* __restrict__ P,
                                                  const float* __restrict__ Q)
{
    int tid = blockIdx.x * 256 + threadIdx.x;  // 0..65535
    int n = tid & 15;
    int d = (tid >> 4) & (DI - 1);
    int b = tid >> 14;
    float carry = 0.f;
    for (int c = 0; c < NCH; ++c) {
        size_t idx = ((size_t)(b * NCH + c) * DI + d) * DS + n;
        float Pv = P[idx], Qv = Q[idx];
        P[idx] = carry;                 // state entering chunk c
        carry = fmaf(Pv, carry, Qv);
    }
}

// pass3: same mapping as pass1; re-run recurrence from H_in, reduce over n,
// fuse D-skip + silu(z) gate. Writes y in place over delta (same-wave
// load-before-store within each iteration; both pointers NOT __restrict__).
__global__ __launch_bounds__(1024) void scan_pass3(
    const float* delta, const float* __restrict__ xs,
    const float* __restrict__ dbc, const float* __restrict__ xz,
    const float* __restrict__ A_log, const float* __restrict__ Dsk,
    const float* __restrict__ Hin, float* yz)
{
    const int tid = threadIdx.x;
    const int n = tid & 15;
    const int dlo = (tid >> 4) & 63;
    const int dgrp = blockIdx.x & 15;
    const int chunk = (blockIdx.x >> 4) & 15;
    const int b = blockIdx.x >> 8;
    const int d = dgrp * 64 + dlo;
    const float An = -__expf(A_log[d * DS + n]);
    const float Dd = Dsk[d];
    const int t0 = b * LL + chunk * CH;
    const float* dp = delta + (size_t)t0 * DI + d;
    const float* xp = xs + (size_t)t0 * DI + d;
    const float* bp = dbc + (size_t)t0 * NX + DTR + n;
    const float* cp = dbc + (size_t)t0 * NX + DTR + DS + n;
    const float* zp = xz + (size_t)t0 * 2048 + DI + d;
    float* yp = yz + (size_t)t0 * DI + d;

    float h = Hin[((size_t)(b * NCH + chunk) * DI + d) * DS + n];

    for (int t = 0; t < CH; ++t) {
        float dlt = dp[t * DI];
        float xv  = xp[t * DI];
        float Bn  = bp[t * NX];
        float Cn  = cp[t * NX];
        float zv  = zp[t * 2048];
        float dA = __expf(dlt * An);
        h = fmaf(dA, h, dlt * xv * Bn);
        float p = h * Cn;
        p += __shfl_xor(p, 1);
        p += __shfl_xor(p, 2);
        p += __shfl_xor(p, 4);
        p += __shfl_xor(p, 8);
        if (n == 0) {
            float y = p + xv * Dd;
            float sz = zv / (1.f + __expf(-zv));
            yp[t * DI] = y * sz;
        }
    }
}

// ---------------------------------------------------------------------------
// residual add + LayerNorm; hprev and hout must not alias
__global__ __launch_bounds__(512) void ln_kernel(
    const float* __restrict__ o, const float* __restrict__ hprev,
    const float* __restrict__ g, const float* __restrict__ bta,
    float* __restrict__ hout)
{
    int row = blockIdx.x, c = threadIdx.x;
    size_t off = (size_t)row * DM + c;
    float v = o[off] + hprev[off];
    float s1 = v, s2 = v * v;
#pragma unroll
    for (int m = 32; m >= 1; m >>= 1) {
        s1 += __shfl_xor(s1, m);
        s2 += __shfl_xor(s2, m);
    }
    __shared__ float r1[8], r2[8];
    __shared__ float stats[2];
    int w = c >> 6;
    if ((c & 63) == 0) { r1[w] = s1; r2[w] = s2; }
    __syncthreads();
    if (c == 0) {
        float a = 0.f, q = 0.f;
        for (int i = 0; i < 8; ++i) { a += r1[i]; q += r2[i]; }
        float mean = a / (float)DM;
        float var = q / (float)DM - mean * mean;
        stats[0] = mean;
        stats[1] = rsqrtf(var + 1e-5f);
    }
    __syncthreads();
    hout[off] = (v - stats[0]) * stats[1] * g[c] + bta[c];
}

// ---------------------------------------------------------------------------
extern "C" void kernel_launch(void* const* d_in, const int* in_sizes, int n_in,
                              void* d_out, int out_size, void* d_ws, size_t ws_size,
                              hipStream_t stream)
{
    const float* x    = (const float*)d_in[0];
    const float* Wi   = (const float*)d_in[1];
    const float* cw   = (const float*)d_in[2];
    const float* cb   = (const float*)d_in[3];
    const float* Wx   = (const float*)d_in[4];
    const float* Wdt  = (const float*)d_in[5];
    const float* bdt  = (const float*)d_in[6];
    const float* Alog = (const float*)d_in[7];
    const float* Dsk  = (const float*)d_in[8];
    const float* Wo   = (const float*)d_in[9];
    const float* lng  = (const float*)d_in[10];
    const float* lnb  = (const float*)d_in[11];

    // workspace layout (floats). total 20.25M floats = 81 MB
    float* ws   = (float*)d_ws;
    float* h    = ws;                        // 2M   (4096 x 512)
    float* xzb  = h + 2 * 1024 * 1024;       // 8M   (4096 x 2048)
    float* xsb  = xzb + 8 * 1024 * 1024;     // 4M   (4096 x 1024)
    float* dbc  = xsb + 4 * 1024 * 1024;     // 256K (4096 x 64)
    float* dlt  = dbc + 262144;              // 4M   (4096 x 1024); scan writes yz here in place
    float* ob   = dlt + 4 * 1024 * 1024;     // 2M   (4096 x 512)
    // scan scratch: reuse ob (idle during scan). P/Hin = 1M floats, Q = 1M floats
    float* Pb = ob;
    float* Qb = ob + 1024 * 1024;

    for (int l = 0; l < 2; ++l) {
        const float* hin = (l == 0) ? x : h;

        // xz = hin @ Wi[l]   (4096 x 2048, K=512)
        gemm_k<0><<<dim3(2048 / 64, MROWS / 64, 1), 256, 0, stream>>>(
            hin, Wi + (size_t)l * DM * 2048, xzb, MROWS, 2048, DM, DM, nullptr, DM);

        // xs = silu(conv(xin) + cb)
        conv_silu_kernel<<<MROWS * DI / 256, 256, 0, stream>>>(
            xzb, cw + (size_t)l * DI * 4, cb + (size_t)l * DI, xsb);

        // dbc = xs @ Wx[l]  (4096 x 64, K=1024, split-K=8 with atomics)
        hipMemsetAsync(dbc, 0, (size_t)MROWS * NX * sizeof(float), stream);
        gemm_k<2><<<dim3(1, MROWS / 64, 8), 256, 0, stream>>>(
            xsb, Wx + (size_t)l * DI * NX, dbc, MROWS, NX, DI, DI, nullptr, DI / 8);

        // delta = softplus(dbc[:, :32] @ Wdt[l] + bdt[l])  (4096 x 1024, K=32)
        gemm_k<1><<<dim3(DI / 64, MROWS / 64, 1), 256, 0, stream>>>(
            dbc, Wdt + (size_t)l * DTR * DI, dlt, MROWS, DI, DTR, NX,
            bdt + (size_t)l * DI, DTR);

        // chunk-parallel selective scan -> yz (in place over dlt)
        scan_pass1<<<BB * NCH * 16, 1024, 0, stream>>>(
            dlt, xsb, dbc, Alog + (size_t)l * DI * DS, Pb, Qb);
        scan_pass2<<<256, 256, 0, stream>>>(Pb, Qb);
        scan_pass3<<<BB * NCH * 16, 1024, 0, stream>>>(
            dlt, xsb, dbc, xzb, Alog + (size_t)l * DI * DS, Dsk + (size_t)l * DI,
            Pb, dlt);

        // o = yz @ Wo[l]  (4096 x 512, K=1024)
        gemm_k<0><<<dim3(DM / 64, MROWS / 64, 1), 256, 0, stream>>>(
            dlt, Wo + (size_t)l * DI * DM, ob, MROWS, DM, DI, DI, nullptr, DI);

        // h = LN(o + hin); last layer writes d_out (f32)
        ln_kernel<<<MROWS, 512, 0, stream>>>(
            ob, hin, lng + (size_t)l * DM, lnb + (size_t)l * DM,
            (l == 1) ? (float*)d_out : h);
    }
}

// Round 4
// 645.372 us; speedup vs baseline: 2.4124x; 1.3864x over previous
//
#include <hip/hip_runtime.h>
#include <cstdint>

// Problem constants
#define BB 4
#define LL 1024
#define DM 512
#define DI 1024
#define DS 16
#define DTR 32
#define NX 64          // DTR + 2*DS
#define MROWS 4096     // B*L
#define CH 64          // scan chunk length
#define NCH 16         // LL / CH

typedef __attribute__((ext_vector_type(8))) short bf16x8;
typedef __attribute__((ext_vector_type(4))) float f32x4;

__device__ __forceinline__ unsigned pack_bf16(float a, float b) {
    union { float f; unsigned u; } ua, ub;
    ua.f = a; ub.f = b;
    unsigned ra = (ua.u + 0x7fffu + ((ua.u >> 16) & 1u)) >> 16;
    unsigned rb = (ub.u + 0x7fffu + ((ub.u >> 16) & 1u)) & 0xffff0000u;
    return ra | rb;
}

// ---------------------------------------------------------------------------
// MFMA bf16 GEMM: C[M,N] f32 = A[M,K] f32 @ Bw[K,N] f32 (both converted to
// bf16 at LDS staging). Tile: TM x 128, 4 waves (2x2), BK=32.
// LDS layout (both A and B^T): row r (m or n), k: byte = r*64 +
//   ((k>>3) ^ (r&3))*16 + (k&7)*2   -- XOR swizzle keeps frag reads and
// staged writes near conflict-free. Frag: lane holds [idx=lane&15][k=quad*8+j].
template <int TM>   // 128 (in_proj) or 64 (out_proj)
__global__ __launch_bounds__(256) void gemm_mfma(
    const float* __restrict__ A, const float* __restrict__ Bw, float* __restrict__ C,
    int M, int N, int K, int lda)
{
    constexpr int NI = TM / 32;            // i-tiles per wave
    __shared__ char lds[TM * 64 + 128 * 64];
    char* As = lds;                        // TM rows x 64B
    char* Bs = lds + TM * 64;              // 128 n-rows x 64B

    const int tid = threadIdx.x;
    const int lane = tid & 63;
    const int wave = tid >> 6;
    const int wm = wave >> 1, wn = wave & 1;
    const int lm = lane & 15, quad = lane >> 4;
    const int row0 = blockIdx.y * TM, col0 = blockIdx.x * 128;

    f32x4 acc[NI][4];
#pragma unroll
    for (int i = 0; i < NI; ++i)
#pragma unroll
        for (int j = 0; j < 4; ++j) acc[i][j] = (f32x4){0.f, 0.f, 0.f, 0.f};

    const int sa_m = tid >> 2;             // 0..63
    const int sa_k = (tid & 3) * 8;        // 0,8,16,24
    const int sb_l = tid & 63;             // n-pair
    const int sb_k = (tid >> 6) * 8;       // 0,8,16,24

    for (int k0 = 0; k0 < K; k0 += 32) {
        // ---- global loads (fp32) ----
        float4 av[TM / 64][2];
#pragma unroll
        for (int h = 0; h < TM / 64; ++h) {
            const float* p = A + (size_t)(row0 + sa_m + h * 64) * lda + k0 + sa_k;
            av[h][0] = *(const float4*)p;
            av[h][1] = *(const float4*)(p + 4);
        }
        float2 bv[8];
#pragma unroll
        for (int j = 0; j < 8; ++j)
            bv[j] = *(const float2*)(Bw + (size_t)(k0 + sb_k + j) * N + col0 + sb_l * 2);

        __syncthreads();   // previous iteration's frag reads done

        // ---- stage A (convert to bf16) ----
#pragma unroll
        for (int h = 0; h < TM / 64; ++h) {
            int m = sa_m + h * 64;
            uint4 w;
            w.x = pack_bf16(av[h][0].x, av[h][0].y);
            w.y = pack_bf16(av[h][0].z, av[h][0].w);
            w.z = pack_bf16(av[h][1].x, av[h][1].y);
            w.w = pack_bf16(av[h][1].z, av[h][1].w);
            *(uint4*)(As + m * 64 + ((((sa_k >> 3) ^ (m & 3))) << 4)) = w;
        }
        // ---- stage B transposed (two n rows) ----
        {
            int n0 = sb_l * 2;
            uint4 w;
            w.x = pack_bf16(bv[0].x, bv[1].x);
            w.y = pack_bf16(bv[2].x, bv[3].x);
            w.z = pack_bf16(bv[4].x, bv[5].x);
            w.w = pack_bf16(bv[6].x, bv[7].x);
            *(uint4*)(Bs + n0 * 64 + ((((sb_k >> 3) ^ (n0 & 3))) << 4)) = w;
            int n1 = n0 + 1;
            w.x = pack_bf16(bv[0].y, bv[1].y);
            w.y = pack_bf16(bv[2].y, bv[3].y);
            w.z = pack_bf16(bv[4].y, bv[5].y);
            w.w = pack_bf16(bv[6].y, bv[7].y);
            *(uint4*)(Bs + n1 * 64 + ((((sb_k >> 3) ^ (n1 & 3))) << 4)) = w;
        }
        __syncthreads();

        // ---- fragments + MFMA ----
        bf16x8 af[NI], bf[4];
#pragma unroll
        for (int i = 0; i < NI; ++i) {
            int r = wm * (TM / 2) + i * 16 + lm;
            af[i] = *(const bf16x8*)(As + r * 64 + ((quad ^ (lm & 3)) << 4));
        }
#pragma unroll
        for (int j = 0; j < 4; ++j) {
            int r = wn * 64 + j * 16 + lm;
            bf[j] = *(const bf16x8*)(Bs + r * 64 + ((quad ^ (lm & 3)) << 4));
        }
#pragma unroll
        for (int i = 0; i < NI; ++i)
#pragma unroll
            for (int j = 0; j < 4; ++j)
                acc[i][j] = __builtin_amdgcn_mfma_f32_16x16x32_bf16(
                    af[i], bf[j], acc[i][j], 0, 0, 0);
    }

    // ---- epilogue: C/D layout col=lane&15, row=quad*4+reg ----
#pragma unroll
    for (int i = 0; i < NI; ++i) {
#pragma unroll
        for (int j = 0; j < 4; ++j) {
#pragma unroll
            for (int r = 0; r < 4; ++r) {
                int row = row0 + wm * (TM / 2) + i * 16 + quad * 4 + r;
                int col = col0 + wn * 64 + j * 16 + lm;
                C[(size_t)row * N + col] = acc[i][j][r];
            }
        }
    }
}

// ---------------------------------------------------------------------------
// Vector tiled GEMM (small shapes): C[M,N] f32 = A[M,K] (lda) @ Bw[K,N]
// EP: 1 = softplus(acc + bias[col]), 2 = atomicAdd (split-K)
template <int EP>
__global__ __launch_bounds__(256) void gemm_k(
    const float* __restrict__ A, const float* __restrict__ Bw, float* __restrict__ C,
    int M, int N, int K, int lda, const float* __restrict__ bias, int kchunk)
{
    __shared__ float As[16][68];
    __shared__ float Bs[16][68];
    const int tid = threadIdx.x;
    const int tx = tid & 15, ty = tid >> 4;
    const int col0 = blockIdx.x * 64, row0 = blockIdx.y * 64;
    const int kstart = blockIdx.z * kchunk;
    const int kend = kstart + kchunk;

    float acc[4][4];
#pragma unroll
    for (int i = 0; i < 4; ++i)
#pragma unroll
        for (int j = 0; j < 4; ++j) acc[i][j] = 0.f;

    const int am = tid >> 2;
    const int ak = (tid & 3) * 4;
    const int bk = tid >> 4;
    const int bn = (tid & 15) * 4;

    for (int k0 = kstart; k0 < kend; k0 += 16) {
        float4 av = *(const float4*)(A + (size_t)(row0 + am) * lda + k0 + ak);
        float4 bv = *(const float4*)(Bw + (size_t)(k0 + bk) * N + col0 + bn);
        __syncthreads();
        As[ak + 0][am] = av.x; As[ak + 1][am] = av.y;
        As[ak + 2][am] = av.z; As[ak + 3][am] = av.w;
        Bs[bk][bn + 0] = bv.x; Bs[bk][bn + 1] = bv.y;
        Bs[bk][bn + 2] = bv.z; Bs[bk][bn + 3] = bv.w;
        __syncthreads();
#pragma unroll
        for (int k = 0; k < 16; ++k) {
            const float4 a = *(const float4*)&As[k][ty * 4];
            const float4 b = *(const float4*)&Bs[k][tx * 4];
            acc[0][0] += a.x * b.x; acc[0][1] += a.x * b.y; acc[0][2] += a.x * b.z; acc[0][3] += a.x * b.w;
            acc[1][0] += a.y * b.x; acc[1][1] += a.y * b.y; acc[1][2] += a.y * b.z; acc[1][3] += a.y * b.w;
            acc[2][0] += a.z * b.x; acc[2][1] += a.z * b.y; acc[2][2] += a.z * b.z; acc[2][3] += a.z * b.w;
            acc[3][0] += a.w * b.x; acc[3][1] += a.w * b.y; acc[3][2] += a.w * b.z; acc[3][3] += a.w * b.w;
        }
    }

#pragma unroll
    for (int i = 0; i < 4; ++i) {
        int row = row0 + ty * 4 + i;
#pragma unroll
        for (int j = 0; j < 4; ++j) {
            int col = col0 + tx * 4 + j;
            float v = acc[i][j];
            size_t addr = (size_t)row * N + col;
            if (EP == 1) {
                v += bias[col];
                float ax = fabsf(v);
                v = fmaxf(v, 0.f) + log1pf(__expf(-ax));
                C[addr] = v;
            } else if (EP == 2) {
                atomicAdd(&C[addr], v);
            } else {
                C[addr] = v;
            }
        }
    }
}

// ---------------------------------------------------------------------------
// depthwise causal conv (kernel 4) + bias + SiLU
__global__ void conv_silu_kernel(const float* __restrict__ xz,
                                 const float* __restrict__ cw, const float* __restrict__ cb,
                                 float* __restrict__ xs)
{
    int idx = blockIdx.x * blockDim.x + threadIdx.x;   // 0 .. 4M-1
    int d = idx & (DI - 1);
    int bt = idx >> 10;
    int t = bt & (LL - 1);
    float acc = cb[d];
#pragma unroll
    for (int k = 0; k < 4; ++k) {
        int tt = t - 3 + k;
        if (tt >= 0) acc += xz[(size_t)(bt - 3 + k) * 2048 + d] * cw[d * 4 + k];
    }
    xs[idx] = acc / (1.f + __expf(-acc));
}

// ---------------------------------------------------------------------------
// Chunked parallel scan (3 passes). See round-3 notes.
__global__ __launch_bounds__(1024) void scan_pass1(
    const float* __restrict__ delta, const float* __restrict__ xs,
    const float* __restrict__ dbc, const float* __restrict__ A_log,
    float* __restrict__ P, float* __restrict__ Q)
{
    const int tid = threadIdx.x;
    const int n = tid & 15;
    const int dlo = (tid >> 4) & 63;
    const int dgrp = blockIdx.x & 15;
    const int chunk = (blockIdx.x >> 4) & 15;
    const int b = blockIdx.x >> 8;
    const int d = dgrp * 64 + dlo;
    const float An = -__expf(A_log[d * DS + n]);
    const int t0 = b * LL + chunk * CH;
    const float* dp = delta + (size_t)t0 * DI + d;
    const float* xp = xs + (size_t)t0 * DI + d;
    const float* bp = dbc + (size_t)t0 * NX + DTR + n;
    float Pv = 1.f, h = 0.f;
    for (int t = 0; t < CH; ++t) {
        float dlt = dp[t * DI];
        float xv  = xp[t * DI];
        float Bn  = bp[t * NX];
        float dA = __expf(dlt * An);
        Pv *= dA;
        h = fmaf(dA, h, dlt * xv * Bn);
    }
    size_t idx = ((size_t)(b * NCH + chunk) * DI + d) * DS + n;
    P[idx] = Pv;
    Q[idx] = h;
}

__global__ __launch_bounds__(256) void scan_pass2(float* __restrict__ P,
                                                  const float* __restrict__ Q)
{
    int tid = blockIdx.x * 256 + threadIdx.x;
    int n = tid & 15;
    int d = (tid >> 4) & (DI - 1);
    int b = tid >> 14;
    float carry = 0.f;
    for (int c = 0; c < NCH; ++c) {
        size_t idx = ((size_t)(b * NCH + c) * DI + d) * DS + n;
        float Pv = P[idx], Qv = Q[idx];
        P[idx] = carry;
        carry = fmaf(Pv, carry, Qv);
    }
}

__global__ __launch_bounds__(1024) void scan_pass3(
    const float* delta, const float* __restrict__ xs,
    const float* __restrict__ dbc, const float* __restrict__ xz,
    const float* __restrict__ A_log, const float* __restrict__ Dsk,
    const float* __restrict__ Hin, float* yz)
{
    const int tid = threadIdx.x;
    const int n = tid & 15;
    const int dlo = (tid >> 4) & 63;
    const int dgrp = blockIdx.x & 15;
    const int chunk = (blockIdx.x >> 4) & 15;
    const int b = blockIdx.x >> 8;
    const int d = dgrp * 64 + dlo;
    const float An = -__expf(A_log[d * DS + n]);
    const float Dd = Dsk[d];
    const int t0 = b * LL + chunk * CH;
    const float* dp = delta + (size_t)t0 * DI + d;
    const float* xp = xs + (size_t)t0 * DI + d;
    const float* bp = dbc + (size_t)t0 * NX + DTR + n;
    const float* cp = dbc + (size_t)t0 * NX + DTR + DS + n;
    const float* zp = xz + (size_t)t0 * 2048 + DI + d;
    float* yp = yz + (size_t)t0 * DI + d;

    float h = Hin[((size_t)(b * NCH + chunk) * DI + d) * DS + n];

    for (int t = 0; t < CH; ++t) {
        float dlt = dp[t * DI];
        float xv  = xp[t * DI];
        float Bn  = bp[t * NX];
        float Cn  = cp[t * NX];
        float zv  = zp[t * 2048];
        float dA = __expf(dlt * An);
        h = fmaf(dA, h, dlt * xv * Bn);
        float p = h * Cn;
        p += __shfl_xor(p, 1);
        p += __shfl_xor(p, 2);
        p += __shfl_xor(p, 4);
        p += __shfl_xor(p, 8);
        if (n == 0) {
            float y = p + xv * Dd;
            float sz = zv / (1.f + __expf(-zv));
            yp[t * DI] = y * sz;
        }
    }
}

// ---------------------------------------------------------------------------
// residual add + LayerNorm; hprev and hout must not alias
__global__ __launch_bounds__(512) void ln_kernel(
    const float* __restrict__ o, const float* __restrict__ hprev,
    const float* __restrict__ g, const float* __restrict__ bta,
    float* __restrict__ hout)
{
    int row = blockIdx.x, c = threadIdx.x;
    size_t off = (size_t)row * DM + c;
    float v = o[off] + hprev[off];
    float s1 = v, s2 = v * v;
#pragma unroll
    for (int m = 32; m >= 1; m >>= 1) {
        s1 += __shfl_xor(s1, m);
        s2 += __shfl_xor(s2, m);
    }
    __shared__ float r1[8], r2[8];
    __shared__ float stats[2];
    int w = c >> 6;
    if ((c & 63) == 0) { r1[w] = s1; r2[w] = s2; }
    __syncthreads();
    if (c == 0) {
        float a = 0.f, q = 0.f;
        for (int i = 0; i < 8; ++i) { a += r1[i]; q += r2[i]; }
        float mean = a / (float)DM;
        float var = q / (float)DM - mean * mean;
        stats[0] = mean;
        stats[1] = rsqrtf(var + 1e-5f);
    }
    __syncthreads();
    hout[off] = (v - stats[0]) * stats[1] * g[c] + bta[c];
}

// ---------------------------------------------------------------------------
extern "C" void kernel_launch(void* const* d_in, const int* in_sizes, int n_in,
                              void* d_out, int out_size, void* d_ws, size_t ws_size,
                              hipStream_t stream)
{
    const float* x    = (const float*)d_in[0];
    const float* Wi   = (const float*)d_in[1];
    const float* cw   = (const float*)d_in[2];
    const float* cb   = (const float*)d_in[3];
    const float* Wx   = (const float*)d_in[4];
    const float* Wdt  = (const float*)d_in[5];
    const float* bdt  = (const float*)d_in[6];
    const float* Alog = (const float*)d_in[7];
    const float* Dsk  = (const float*)d_in[8];
    const float* Wo   = (const float*)d_in[9];
    const float* lng  = (const float*)d_in[10];
    const float* lnb  = (const float*)d_in[11];

    float* ws   = (float*)d_ws;
    float* h    = ws;                        // 2M   (4096 x 512)
    float* xzb  = h + 2 * 1024 * 1024;       // 8M   (4096 x 2048)
    float* xsb  = xzb + 8 * 1024 * 1024;     // 4M   (4096 x 1024)
    float* dbc  = xsb + 4 * 1024 * 1024;     // 256K (4096 x 64)
    float* dlt  = dbc + 262144;              // 4M   (4096 x 1024); yz in place
    float* ob   = dlt + 4 * 1024 * 1024;     // 2M   (4096 x 512)
    float* Pb = ob;                          // scan scratch reuses ob
    float* Qb = ob + 1024 * 1024;

    for (int l = 0; l < 2; ++l) {
        const float* hin = (l == 0) ? x : h;

        // xz = hin @ Wi[l]   (4096 x 2048, K=512) -- MFMA
        gemm_mfma<128><<<dim3(2048 / 128, MROWS / 128), 256, 0, stream>>>(
            hin, Wi + (size_t)l * DM * 2048, xzb, MROWS, 2048, DM, DM);

        // xs = silu(conv(xin) + cb)
        conv_silu_kernel<<<MROWS * DI / 256, 256, 0, stream>>>(
            xzb, cw + (size_t)l * DI * 4, cb + (size_t)l * DI, xsb);

        // dbc = xs @ Wx[l]  (4096 x 64, K=1024, split-K=8 with atomics)
        hipMemsetAsync(dbc, 0, (size_t)MROWS * NX * sizeof(float), stream);
        gemm_k<2><<<dim3(1, MROWS / 64, 8), 256, 0, stream>>>(
            xsb, Wx + (size_t)l * DI * NX, dbc, MROWS, NX, DI, DI, nullptr, DI / 8);

        // delta = softplus(dbc[:, :32] @ Wdt[l] + bdt[l])  (4096 x 1024, K=32)
        gemm_k<1><<<dim3(DI / 64, MROWS / 64, 1), 256, 0, stream>>>(
            dbc, Wdt + (size_t)l * DTR * DI, dlt, MROWS, DI, DTR, NX,
            bdt + (size_t)l * DI, DTR);

        // chunk-parallel selective scan -> yz (in place over dlt)
        scan_pass1<<<BB * NCH * 16, 1024, 0, stream>>>(
            dlt, xsb, dbc, Alog + (size_t)l * DI * DS, Pb, Qb);
        scan_pass2<<<256, 256, 0, stream>>>(Pb, Qb);
        scan_pass3<<<BB * NCH * 16, 1024, 0, stream>>>(
            dlt, xsb, dbc, xzb, Alog + (size_t)l * DI * DS, Dsk + (size_t)l * DI,
            Pb, dlt);

        // o = yz @ Wo[l]  (4096 x 512, K=1024) -- MFMA, TM=64 for 256 blocks
        gemm_mfma<64><<<dim3(DM / 128, MROWS / 64), 256, 0, stream>>>(
            dlt, Wo + (size_t)l * DI * DM, ob, MROWS, DM, DI, DI);

        // h = LN(o + hin); last layer writes d_out (f32)
        ln_kernel<<<MROWS, 512, 0, stream>>>(
            ob, hin, lng + (size_t)l * DM, lnb + (size_t)l * DM,
            (l == 1) ? (float*)d_out : h);
    }
}

// Round 5
// 501.840 us; speedup vs baseline: 3.1024x; 1.2860x over previous
//
#include <hip/hip_runtime.h>
#include <cstdint>

// Problem constants
#define BB 4
#define LL 1024
#define DM 512
#define DI 1024
#define DS 16
#define DTR 32
#define NX 64          // DTR + 2*DS
#define MROWS 4096     // B*L
#define CH 32          // scan chunk length
#define NCH 32         // LL / CH
#define PQLIN (BB * NCH * DI * DS)   // 2,097,152 linear elems each for P and Q

typedef __attribute__((ext_vector_type(8))) short bf16x8;
typedef __attribute__((ext_vector_type(4))) float f32x4;

__device__ __forceinline__ unsigned pack_bf16(float a, float b) {
    union { float f; unsigned u; } ua, ub;
    ua.f = a; ub.f = b;
    unsigned ra = (ua.u + 0x7fffu + ((ua.u >> 16) & 1u)) >> 16;
    unsigned rb = (ub.u + 0x7fffu + ((ub.u >> 16) & 1u)) & 0xffff0000u;
    return ra | rb;
}

// P/Q live in the dead xin half of xzb (cols 0..1023; rows 0..4095).
// linear index i in [0, 2*PQLIN) -> float offset within xzb.
__device__ __forceinline__ size_t hole(size_t i) {
    return ((i >> 10) << 11) | (i & 1023);
}

// ---------------------------------------------------------------------------
// MFMA bf16 GEMM: C[M,N] f32 = A[M,K] f32 @ Bw[K,N] f32 (bf16 conversion at
// LDS staging). Tile: TM x 128, 4 waves (2x2), BK=32. XOR-swizzled LDS.
template <int TM>   // 128 (in_proj) or 64 (out_proj)
__global__ __launch_bounds__(256) void gemm_mfma(
    const float* __restrict__ A, const float* __restrict__ Bw, float* __restrict__ C,
    int M, int N, int K, int lda)
{
    constexpr int NI = TM / 32;
    __shared__ char lds[TM * 64 + 128 * 64];
    char* As = lds;
    char* Bs = lds + TM * 64;

    const int tid = threadIdx.x;
    const int lane = tid & 63;
    const int wave = tid >> 6;
    const int wm = wave >> 1, wn = wave & 1;
    const int lm = lane & 15, quad = lane >> 4;
    const int row0 = blockIdx.y * TM, col0 = blockIdx.x * 128;

    f32x4 acc[NI][4];
#pragma unroll
    for (int i = 0; i < NI; ++i)
#pragma unroll
        for (int j = 0; j < 4; ++j) acc[i][j] = (f32x4){0.f, 0.f, 0.f, 0.f};

    const int sa_m = tid >> 2;
    const int sa_k = (tid & 3) * 8;
    const int sb_l = tid & 63;
    const int sb_k = (tid >> 6) * 8;

    for (int k0 = 0; k0 < K; k0 += 32) {
        float4 av[TM / 64][2];
#pragma unroll
        for (int h = 0; h < TM / 64; ++h) {
            const float* p = A + (size_t)(row0 + sa_m + h * 64) * lda + k0 + sa_k;
            av[h][0] = *(const float4*)p;
            av[h][1] = *(const float4*)(p + 4);
        }
        float2 bv[8];
#pragma unroll
        for (int j = 0; j < 8; ++j)
            bv[j] = *(const float2*)(Bw + (size_t)(k0 + sb_k + j) * N + col0 + sb_l * 2);

        __syncthreads();

#pragma unroll
        for (int h = 0; h < TM / 64; ++h) {
            int m = sa_m + h * 64;
            uint4 w;
            w.x = pack_bf16(av[h][0].x, av[h][0].y);
            w.y = pack_bf16(av[h][0].z, av[h][0].w);
            w.z = pack_bf16(av[h][1].x, av[h][1].y);
            w.w = pack_bf16(av[h][1].z, av[h][1].w);
            *(uint4*)(As + m * 64 + ((((sa_k >> 3) ^ (m & 3))) << 4)) = w;
        }
        {
            int n0 = sb_l * 2;
            uint4 w;
            w.x = pack_bf16(bv[0].x, bv[1].x);
            w.y = pack_bf16(bv[2].x, bv[3].x);
            w.z = pack_bf16(bv[4].x, bv[5].x);
            w.w = pack_bf16(bv[6].x, bv[7].x);
            *(uint4*)(Bs + n0 * 64 + ((((sb_k >> 3) ^ (n0 & 3))) << 4)) = w;
            int n1 = n0 + 1;
            w.x = pack_bf16(bv[0].y, bv[1].y);
            w.y = pack_bf16(bv[2].y, bv[3].y);
            w.z = pack_bf16(bv[4].y, bv[5].y);
            w.w = pack_bf16(bv[6].y, bv[7].y);
            *(uint4*)(Bs + n1 * 64 + ((((sb_k >> 3) ^ (n1 & 3))) << 4)) = w;
        }
        __syncthreads();

        bf16x8 af[NI], bf[4];
#pragma unroll
        for (int i = 0; i < NI; ++i) {
            int r = wm * (TM / 2) + i * 16 + lm;
            af[i] = *(const bf16x8*)(As + r * 64 + ((quad ^ (lm & 3)) << 4));
        }
#pragma unroll
        for (int j = 0; j < 4; ++j) {
            int r = wn * 64 + j * 16 + lm;
            bf[j] = *(const bf16x8*)(Bs + r * 64 + ((quad ^ (lm & 3)) << 4));
        }
#pragma unroll
        for (int i = 0; i < NI; ++i)
#pragma unroll
            for (int j = 0; j < 4; ++j)
                acc[i][j] = __builtin_amdgcn_mfma_f32_16x16x32_bf16(
                    af[i], bf[j], acc[i][j], 0, 0, 0);
    }

#pragma unroll
    for (int i = 0; i < NI; ++i) {
#pragma unroll
        for (int j = 0; j < 4; ++j) {
#pragma unroll
            for (int r = 0; r < 4; ++r) {
                int row = row0 + wm * (TM / 2) + i * 16 + quad * 4 + r;
                int col = col0 + wn * 64 + j * 16 + lm;
                C[(size_t)row * N + col] = acc[i][j][r];
            }
        }
    }
}

// ---------------------------------------------------------------------------
// Vector tiled GEMM (small shapes). EP: 1 = softplus(acc+bias), 2 = atomicAdd
template <int EP>
__global__ __launch_bounds__(256) void gemm_k(
    const float* __restrict__ A, const float* __restrict__ Bw, float* __restrict__ C,
    int M, int N, int K, int lda, const float* __restrict__ bias, int kchunk)
{
    __shared__ float As[16][68];
    __shared__ float Bs[16][68];
    const int tid = threadIdx.x;
    const int tx = tid & 15, ty = tid >> 4;
    const int col0 = blockIdx.x * 64, row0 = blockIdx.y * 64;
    const int kstart = blockIdx.z * kchunk;
    const int kend = kstart + kchunk;

    float acc[4][4];
#pragma unroll
    for (int i = 0; i < 4; ++i)
#pragma unroll
        for (int j = 0; j < 4; ++j) acc[i][j] = 0.f;

    const int am = tid >> 2;
    const int ak = (tid & 3) * 4;
    const int bk = tid >> 4;
    const int bn = (tid & 15) * 4;

    for (int k0 = kstart; k0 < kend; k0 += 16) {
        float4 av = *(const float4*)(A + (size_t)(row0 + am) * lda + k0 + ak);
        float4 bv = *(const float4*)(Bw + (size_t)(k0 + bk) * N + col0 + bn);
        __syncthreads();
        As[ak + 0][am] = av.x; As[ak + 1][am] = av.y;
        As[ak + 2][am] = av.z; As[ak + 3][am] = av.w;
        Bs[bk][bn + 0] = bv.x; Bs[bk][bn + 1] = bv.y;
        Bs[bk][bn + 2] = bv.z; Bs[bk][bn + 3] = bv.w;
        __syncthreads();
#pragma unroll
        for (int k = 0; k < 16; ++k) {
            const float4 a = *(const float4*)&As[k][ty * 4];
            const float4 b = *(const float4*)&Bs[k][tx * 4];
            acc[0][0] += a.x * b.x; acc[0][1] += a.x * b.y; acc[0][2] += a.x * b.z; acc[0][3] += a.x * b.w;
            acc[1][0] += a.y * b.x; acc[1][1] += a.y * b.y; acc[1][2] += a.y * b.z; acc[1][3] += a.y * b.w;
            acc[2][0] += a.z * b.x; acc[2][1] += a.z * b.y; acc[2][2] += a.z * b.z; acc[2][3] += a.z * b.w;
            acc[3][0] += a.w * b.x; acc[3][1] += a.w * b.y; acc[3][2] += a.w * b.z; acc[3][3] += a.w * b.w;
        }
    }

#pragma unroll
    for (int i = 0; i < 4; ++i) {
        int row = row0 + ty * 4 + i;
#pragma unroll
        for (int j = 0; j < 4; ++j) {
            int col = col0 + tx * 4 + j;
            float v = acc[i][j];
            size_t addr = (size_t)row * N + col;
            if (EP == 1) {
                v += bias[col];
                float ax = fabsf(v);
                v = fmaxf(v, 0.f) + log1pf(__expf(-ax));
                C[addr] = v;
            } else if (EP == 2) {
                atomicAdd(&C[addr], v);
            } else {
                C[addr] = v;
            }
        }
    }
}

// ---------------------------------------------------------------------------
// depthwise causal conv (kernel 4) + bias + SiLU
__global__ void conv_silu_kernel(const float* __restrict__ xz,
                                 const float* __restrict__ cw, const float* __restrict__ cb,
                                 float* __restrict__ xs)
{
    int idx = blockIdx.x * blockDim.x + threadIdx.x;
    int d = idx & (DI - 1);
    int bt = idx >> 10;
    int t = bt & (LL - 1);
    float acc = cb[d];
#pragma unroll
    for (int k = 0; k < 4; ++k) {
        int tt = t - 3 + k;
        if (tt >= 0) acc += xz[(size_t)(bt - 3 + k) * 2048 + d] * cw[d * 4 + k];
    }
    xs[idx] = acc / (1.f + __expf(-acc));
}

// ---------------------------------------------------------------------------
// Chunk-parallel scan, register-state version: one thread owns all DS=16
// states of one (b, chunk, d). B/C rows staged in LDS (shared across d).
// pass1: local scan -> P = prod(dA), Q = local h; stored in xzb holes.
__global__ __launch_bounds__(256) void scan_pass1(
    const float* __restrict__ delta, const float* __restrict__ xs,
    const float* __restrict__ dbc, const float* __restrict__ A_log,
    float* __restrict__ PQ)
{
    const int dgrp = blockIdx.x & 3;
    const int chunk = (blockIdx.x >> 2) & (NCH - 1);
    const int b = blockIdx.x >> 7;
    const int d = dgrp * 256 + threadIdx.x;
    const int t0 = b * LL + chunk * CH;

    __shared__ float sB[CH][DS];
    {
        int i = threadIdx.x;               // 0..255 -> 2 floats each
        int row = i >> 3, col = (i & 7) * 2;
        float2 v = *(const float2*)(dbc + (size_t)(t0 + row) * NX + DTR + col);
        sB[row][col] = v.x; sB[row][col + 1] = v.y;
    }
    float An[DS];
#pragma unroll
    for (int n = 0; n < DS; ++n) An[n] = -__expf(A_log[d * DS + n]);
    __syncthreads();

    float P[DS], h[DS];
#pragma unroll
    for (int n = 0; n < DS; ++n) { P[n] = 1.f; h[n] = 0.f; }

    const float* dp = delta + (size_t)t0 * DI + d;
    const float* xp = xs + (size_t)t0 * DI + d;
#pragma unroll 4
    for (int t = 0; t < CH; ++t) {
        float dlt = dp[t * DI];
        float du = dlt * xp[t * DI];
#pragma unroll
        for (int n = 0; n < DS; ++n) {
            float dA = __expf(dlt * An[n]);
            P[n] *= dA;
            h[n] = fmaf(dA, h[n], du * sB[t][n]);
        }
    }
    size_t base = ((size_t)(b * NCH + chunk) * DI + d) * DS;
    float4* Pp = (float4*)(PQ + hole(base));
    float4* Qp = (float4*)(PQ + hole(base + PQLIN));
#pragma unroll
    for (int g = 0; g < 4; ++g) {
        Pp[g] = make_float4(P[g * 4], P[g * 4 + 1], P[g * 4 + 2], P[g * 4 + 3]);
        Qp[g] = make_float4(h[g * 4], h[g * 4 + 1], h[g * 4 + 2], h[g * 4 + 3]);
    }
}

// pass2: thread per (b,d,n); serial over NCH chunks; P slot becomes H_in
__global__ __launch_bounds__(256) void scan_pass2(float* __restrict__ PQ)
{
    int tid = blockIdx.x * 256 + threadIdx.x;
    int n = tid & 15;
    int d = (tid >> 4) & (DI - 1);
    int b = tid >> 14;
    float carry = 0.f;
    for (int c = 0; c < NCH; ++c) {
        size_t i = ((size_t)(b * NCH + c) * DI + d) * DS + n;
        float Pv = PQ[hole(i)];
        float Qv = PQ[hole(i + PQLIN)];
        PQ[hole(i)] = carry;
        carry = fmaf(Pv, carry, Qv);
    }
}

// pass3: re-run recurrence from H_in; y = sum_n h_n C_n; fuse D-skip + silu(z)
// gate. Writes y in place over delta (same-thread same-address, program order).
__global__ __launch_bounds__(256) void scan_pass3(
    const float* delta, const float* __restrict__ xs,
    const float* __restrict__ dbc, const float* __restrict__ xz,
    const float* __restrict__ A_log, const float* __restrict__ Dsk,
    const float* __restrict__ PQ, float* yz)
{
    const int dgrp = blockIdx.x & 3;
    const int chunk = (blockIdx.x >> 2) & (NCH - 1);
    const int b = blockIdx.x >> 7;
    const int d = dgrp * 256 + threadIdx.x;
    const int t0 = b * LL + chunk * CH;

    __shared__ float sBC[CH][32];   // cols 0..15 = B, 16..31 = C
    {
        int i = threadIdx.x;               // 0..255 -> 4 floats each
        int row = i >> 3, col = (i & 7) * 4;
        float4 v = *(const float4*)(dbc + (size_t)(t0 + row) * NX + DTR + col);
        *(float4*)&sBC[row][col] = v;
    }
    float An[DS];
#pragma unroll
    for (int n = 0; n < DS; ++n) An[n] = -__expf(A_log[d * DS + n]);
    const float Dd = Dsk[d];

    float h[DS];
    {
        size_t base = ((size_t)(b * NCH + chunk) * DI + d) * DS;
        const float4* Hp = (const float4*)(PQ + hole(base));
#pragma unroll
        for (int g = 0; g < 4; ++g) {
            float4 v = Hp[g];
            h[g * 4] = v.x; h[g * 4 + 1] = v.y; h[g * 4 + 2] = v.z; h[g * 4 + 3] = v.w;
        }
    }
    __syncthreads();

    const float* dp = delta + (size_t)t0 * DI + d;
    const float* xp = xs + (size_t)t0 * DI + d;
    const float* zp = xz + (size_t)t0 * 2048 + DI + d;
    float* yp = yz + (size_t)t0 * DI + d;

#pragma unroll 4
    for (int t = 0; t < CH; ++t) {
        float dlt = dp[t * DI];
        float xv  = xp[t * DI];
        float zv  = zp[t * 2048];
        float du = dlt * xv;
        float y = 0.f;
#pragma unroll
        for (int n = 0; n < DS; ++n) {
            float dA = __expf(dlt * An[n]);
            h[n] = fmaf(dA, h[n], du * sBC[t][n]);
            y = fmaf(h[n], sBC[t][DS + n], y);
        }
        y += xv * Dd;
        float sz = zv / (1.f + __expf(-zv));
        yp[t * DI] = y * sz;
    }
}

// ---------------------------------------------------------------------------
// residual add + LayerNorm; hprev and hout must not alias
__global__ __launch_bounds__(512) void ln_kernel(
    const float* __restrict__ o, const float* __restrict__ hprev,
    const float* __restrict__ g, const float* __restrict__ bta,
    float* __restrict__ hout)
{
    int row = blockIdx.x, c = threadIdx.x;
    size_t off = (size_t)row * DM + c;
    float v = o[off] + hprev[off];
    float s1 = v, s2 = v * v;
#pragma unroll
    for (int m = 32; m >= 1; m >>= 1) {
        s1 += __shfl_xor(s1, m);
        s2 += __shfl_xor(s2, m);
    }
    __shared__ float r1[8], r2[8];
    __shared__ float stats[2];
    int w = c >> 6;
    if ((c & 63) == 0) { r1[w] = s1; r2[w] = s2; }
    __syncthreads();
    if (c == 0) {
        float a = 0.f, q = 0.f;
        for (int i = 0; i < 8; ++i) { a += r1[i]; q += r2[i]; }
        float mean = a / (float)DM;
        float var = q / (float)DM - mean * mean;
        stats[0] = mean;
        stats[1] = rsqrtf(var + 1e-5f);
    }
    __syncthreads();
    hout[off] = (v - stats[0]) * stats[1] * g[c] + bta[c];
}

// ---------------------------------------------------------------------------
extern "C" void kernel_launch(void* const* d_in, const int* in_sizes, int n_in,
                              void* d_out, int out_size, void* d_ws, size_t ws_size,
                              hipStream_t stream)
{
    const float* x    = (const float*)d_in[0];
    const float* Wi   = (const float*)d_in[1];
    const float* cw   = (const float*)d_in[2];
    const float* cb   = (const float*)d_in[3];
    const float* Wx   = (const float*)d_in[4];
    const float* Wdt  = (const float*)d_in[5];
    const float* bdt  = (const float*)d_in[6];
    const float* Alog = (const float*)d_in[7];
    const float* Dsk  = (const float*)d_in[8];
    const float* Wo   = (const float*)d_in[9];
    const float* lng  = (const float*)d_in[10];
    const float* lnb  = (const float*)d_in[11];

    float* ws   = (float*)d_ws;
    float* h    = ws;                        // 2M   (4096 x 512)
    float* xzb  = h + 2 * 1024 * 1024;       // 8M   (4096 x 2048); xin half doubles as P/Q
    float* xsb  = xzb + 8 * 1024 * 1024;     // 4M   (4096 x 1024)
    float* dbc  = xsb + 4 * 1024 * 1024;     // 256K (4096 x 64)
    float* dlt  = dbc + 262144;              // 4M   (4096 x 1024); yz in place
    float* ob   = dlt + 4 * 1024 * 1024;     // 2M   (4096 x 512)

    for (int l = 0; l < 2; ++l) {
        const float* hin = (l == 0) ? x : h;

        // xz = hin @ Wi[l]   (4096 x 2048, K=512) -- MFMA
        gemm_mfma<128><<<dim3(2048 / 128, MROWS / 128), 256, 0, stream>>>(
            hin, Wi + (size_t)l * DM * 2048, xzb, MROWS, 2048, DM, DM);

        // xs = silu(conv(xin) + cb)   [consumes xin; holes become free]
        conv_silu_kernel<<<MROWS * DI / 256, 256, 0, stream>>>(
            xzb, cw + (size_t)l * DI * 4, cb + (size_t)l * DI, xsb);

        // dbc = xs @ Wx[l]  (4096 x 64, K=1024, split-K=8 with atomics)
        hipMemsetAsync(dbc, 0, (size_t)MROWS * NX * sizeof(float), stream);
        gemm_k<2><<<dim3(1, MROWS / 64, 8), 256, 0, stream>>>(
            xsb, Wx + (size_t)l * DI * NX, dbc, MROWS, NX, DI, DI, nullptr, DI / 8);

        // delta = softplus(dbc[:, :32] @ Wdt[l] + bdt[l])  (4096 x 1024, K=32)
        gemm_k<1><<<dim3(DI / 64, MROWS / 64, 1), 256, 0, stream>>>(
            dbc, Wdt + (size_t)l * DTR * DI, dlt, MROWS, DI, DTR, NX,
            bdt + (size_t)l * DI, DTR);

        // chunk-parallel selective scan -> yz (in place over dlt)
        scan_pass1<<<BB * NCH * 4, 256, 0, stream>>>(
            dlt, xsb, dbc, Alog + (size_t)l * DI * DS, xzb);
        scan_pass2<<<256, 256, 0, stream>>>(xzb);
        scan_pass3<<<BB * NCH * 4, 256, 0, stream>>>(
            dlt, xsb, dbc, xzb, Alog + (size_t)l * DI * DS, Dsk + (size_t)l * DI,
            xzb, dlt);

        // o = yz @ Wo[l]  (4096 x 512, K=1024) -- MFMA, TM=64 for 256 blocks
        gemm_mfma<64><<<dim3(DM / 128, MROWS / 64), 256, 0, stream>>>(
            dlt, Wo + (size_t)l * DI * DM, ob, MROWS, DM, DI, DI);

        // h = LN(o + hin); last layer writes d_out (f32)
        ln_kernel<<<MROWS, 512, 0, stream>>>(
            ob, hin, lng + (size_t)l * DM, lnb + (size_t)l * DM,
            (l == 1) ? (float*)d_out : h);
    }
}